// Round 8
// baseline (192.688 us; speedup 1.0000x reference)
//
#include <hip/hip_runtime.h>
#include <math.h>

using u16 = unsigned short;
typedef __attribute__((ext_vector_type(8))) __bf16 bf16x8;
typedef __attribute__((ext_vector_type(4))) float f32x4;
typedef __attribute__((ext_vector_type(4))) float f4v;
typedef __attribute__((ext_vector_type(8))) u16 u16x8;

__device__ __forceinline__ u16 f2bf(float f) {
  unsigned u = __float_as_uint(f);
  u += 0x7fffu + ((u >> 16) & 1u);   // round-to-nearest-even
  return (u16)(u >> 16);
}
__device__ __forceinline__ float bf2f(u16 b) {
  unsigned u = ((unsigned)b) << 16;
  return __uint_as_float(u);
}

__device__ __forceinline__ void gload16(const void* g, void* l) {
  __builtin_amdgcn_global_load_lds(
      (const __attribute__((address_space(1))) unsigned int*)g,
      (__attribute__((address_space(3))) unsigned int*)l, 16, 0, 0);
}

__device__ __forceinline__ f32x4 MF(bf16x8 a, bf16x8 b, f32x4 c) {
  return __builtin_amdgcn_mfma_f32_16x16x32_bf16(a, b, c, 0, 0, 0);
}

__device__ __forceinline__ bf16x8 pk8(f4v a, f4v b) {
  bf16x8 x;
  x[0] = (__bf16)a[0]; x[1] = (__bf16)a[1]; x[2] = (__bf16)a[2]; x[3] = (__bf16)a[3];
  x[4] = (__bf16)b[0]; x[5] = (__bf16)b[1]; x[6] = (__bf16)b[2]; x[7] = (__bf16)b[3];
  return x;
}

// ---------------------------------------------------------------- cast f32->bf16 (z-indexed)
__global__ __launch_bounds__(256) void cast3_f32_bf16(
    const float* __restrict__ p0, const float* __restrict__ p1,
    const float* __restrict__ p2, u16* __restrict__ out, size_t ostride) {
  int z = blockIdx.z;
  const float* in = (z == 0) ? p0 : (z == 1) ? p1 : p2;
  size_t i = ((size_t)blockIdx.x * 256 + threadIdx.x) * 8;
  f4v a = *reinterpret_cast<const f4v*>(in + i);
  f4v b = *reinterpret_cast<const f4v*>(in + i + 4);
  u16x8 r;
  r[0] = f2bf(a[0]); r[1] = f2bf(a[1]); r[2] = f2bf(a[2]); r[3] = f2bf(a[3]);
  r[4] = f2bf(b[0]); r[5] = f2bf(b[1]); r[6] = f2bf(b[2]); r[7] = f2bf(b[3]);
  *reinterpret_cast<u16x8*>(out + z * ostride + i) = r;
}

// ---------------------------------------------------------------- transpose+cast f32 W -> bf16 W^T
// z=0: Wk -> WkT; z=1: Wq -> WqT. 1024x1024 each; out[e][d] = in[d][e].
__global__ __launch_bounds__(256) void tcast_w(
    const float* __restrict__ wk, const float* __restrict__ wq,
    u16* __restrict__ wkT, u16* __restrict__ wqT) {
  __shared__ float t[64][65];
  int z = blockIdx.z;
  const float* I = z ? wq : wk;
  u16* O = z ? wqT : wkT;
  int c0 = blockIdx.x * 64, r0 = blockIdx.y * 64;
  int tx = threadIdx.x & 63, ty = threadIdx.x >> 6;
  #pragma unroll
  for (int i = 0; i < 64; i += 4)
    t[ty + i][tx] = I[(size_t)(r0 + ty + i) * 1024 + c0 + tx];
  __syncthreads();
  #pragma unroll
  for (int i = 0; i < 64; i += 4)
    O[(size_t)(c0 + ty + i) * 1024 + r0 + tx] = f2bf(t[tx][ty + i]);
}

// ---------------------------------------------------------------- bf16 transpose
// in: [4][2048][1024]  -> out: [4][1024][2048]
__global__ __launch_bounds__(256) void transpose_bf16k(const u16* __restrict__ in,
                                                       u16* __restrict__ out) {
  __shared__ u16 t[64][65];
  int c0 = blockIdx.x * 64, r0 = blockIdx.y * 64;
  size_t zb = (size_t)blockIdx.z * 2048 * 1024;
  const u16* I = in + zb;
  u16* O = out + zb;
  int tx = threadIdx.x & 63, ty = threadIdx.x >> 6;
  #pragma unroll
  for (int i = 0; i < 64; i += 4)
    t[ty + i][tx] = I[(size_t)(r0 + ty + i) * 1024 + c0 + tx];
  __syncthreads();
  #pragma unroll
  for (int i = 0; i < 64; i += 4)
    O[(size_t)(c0 + ty + i) * 2048 + r0 + tx] = t[tx][ty + i];
}

// ================================================================ fused-cast projection GEMM
// 2 slabs: which=0: Yq = (f32 Xq).(Mt)^T  (Mt = Wk^T.Wq => Yq = Xq.M, M=Wq^T.Wk)
//          which=1: Vp = (f32 Xv).(Wv_bf)^T
// Depth-2 A reg-staging + counted vmcnt(4) raw-barrier protocol (see R7).
// Grid 1024 flat, XCD-chunked.
__global__ __launch_bounds__(256) void proj_fused(
    const float* __restrict__ Aq, const float* __restrict__ Av,
    const u16* __restrict__ W,   // [2][1024][1024]: slab0=Mt, slab1=Wv_bf
    u16* __restrict__ Yq, u16* __restrict__ Vp) {
  int h = blockIdx.x;
  int l = (h & 7) * 128 + (h >> 3);    // bijective XCD chunking
  int bn = l & 7;
  int bm128 = l >> 3;
  int which = bm128 >> 6;
  int bm = bm128 & 63;
  const float* Ag = (which == 0 ? Aq : Av) + (size_t)bm * 128 * 1024;
  const u16* Bg = W + (size_t)which * 1048576 + (size_t)bn * 128 * 1024;
  u16* Cg = (which == 0) ? Yq : Vp;

  __shared__ __align__(16) u16 As[2][128 * 32];   // 2 x 8KB
  __shared__ __align__(16) u16 Bs[2][128 * 32];   // 2 x 8KB

  const int tid = threadIdx.x, lane = tid & 63, wave = tid >> 6;
  const int wr = wave >> 1, wc = wave & 1;
  const int fr = lane & 15, kq = (lane >> 4) * 8;

  const float* ag0 = Ag + (size_t)(tid >> 2) * 1024 + (tid & 3) * 8;
  const float* ag1 = ag0 + 64 * 1024;
  const int w0i = (tid >> 2) * 32 + (tid & 3) * 8;
  const int w1i = w0i + 2048;
  const int ch0 = wave, ch1 = wave + 4;
  const int e0 = ch0 * 512 + lane * 8, e1 = ch1 * 512 + lane * 8;
  const int br0 = e0 >> 5, bc0 = e0 & 31, br1 = e1 >> 5, bc1 = e1 & 31;
  const u16* b0 = Bg + (size_t)br0 * 1024 + bc0;
  const u16* b1 = Bg + (size_t)br1 * 1024 + bc1;

  f32x4 acc[4][4] = {};
  f4v pc0, pc1, pc2, pc3, pn0, pn1, pn2, pn3;

  gload16(b0, &Bs[0][ch0 * 512]);
  gload16(b1, &Bs[0][ch1 * 512]);
  pc0 = *(const f4v*)(ag0);      pc1 = *(const f4v*)(ag0 + 4);
  pc2 = *(const f4v*)(ag1);      pc3 = *(const f4v*)(ag1 + 4);
  pn0 = *(const f4v*)(ag0 + 32); pn1 = *(const f4v*)(ag0 + 36);
  pn2 = *(const f4v*)(ag1 + 32); pn3 = *(const f4v*)(ag1 + 36);
  *(bf16x8*)&As[0][w0i] = pk8(pc0, pc1);
  *(bf16x8*)&As[0][w1i] = pk8(pc2, pc3);
  pc0 = pn0; pc1 = pn1; pc2 = pn2; pc3 = pn3;
  asm volatile("s_waitcnt vmcnt(4)" ::: "memory");
  asm volatile("s_waitcnt lgkmcnt(0)" ::: "memory");
  __builtin_amdgcn_s_barrier();

  for (int t = 0; t < 32; ++t) {
    const int cur = t & 1;
    if (t < 31) {
      const int k0 = (t + 1) * 32;
      gload16(b0 + k0, &Bs[cur ^ 1][ch0 * 512]);
      gload16(b1 + k0, &Bs[cur ^ 1][ch1 * 512]);
    }
    if (t < 30) {
      const float* ap0 = ag0 + (t + 2) * 32;
      const float* ap1 = ag1 + (t + 2) * 32;
      pn0 = *(const f4v*)(ap0); pn1 = *(const f4v*)(ap0 + 4);
      pn2 = *(const f4v*)(ap1); pn3 = *(const f4v*)(ap1 + 4);
    }
    bf16x8 af[4], bfv[4];
    #pragma unroll
    for (int m = 0; m < 4; ++m)
      af[m] = *reinterpret_cast<const bf16x8*>(&As[cur][(wr * 64 + m * 16 + fr) * 32 + kq]);
    #pragma unroll
    for (int n = 0; n < 4; ++n)
      bfv[n] = *reinterpret_cast<const bf16x8*>(&Bs[cur][(wc * 64 + n * 16 + fr) * 32 + kq]);
    #pragma unroll
    for (int m = 0; m < 4; ++m)
      #pragma unroll
      for (int n = 0; n < 4; ++n)
        acc[m][n] = MF(af[m], bfv[n], acc[m][n]);
    if (t < 31) {
      *(bf16x8*)&As[cur ^ 1][w0i] = pk8(pc0, pc1);
      *(bf16x8*)&As[cur ^ 1][w1i] = pk8(pc2, pc3);
      pc0 = pn0; pc1 = pn1; pc2 = pn2; pc3 = pn3;
      if (t < 30) { asm volatile("s_waitcnt vmcnt(4)" ::: "memory"); }
      else        { asm volatile("s_waitcnt vmcnt(0)" ::: "memory"); }
      asm volatile("s_waitcnt lgkmcnt(0)" ::: "memory");
      __builtin_amdgcn_s_barrier();
    }
  }

  const int row0 = bm * 128 + wr * 64 + (lane >> 4) * 4;
  const int col0 = bn * 128 + wc * 64 + fr;
  #pragma unroll
  for (int m = 0; m < 4; ++m)
    #pragma unroll
    for (int n = 0; n < 4; ++n)
      #pragma unroll
      for (int j = 0; j < 4; ++j)
        Cg[(size_t)(row0 + m * 16 + j) * 1024 + (col0 + n * 16)] = f2bf(acc[m][n][j]);
}

// ---------------------------------------------------------------- GEMM  C = alpha * A . B^T
// MODE 0: plain small (grid M/128 x 8), used for Mt = WkT . WqT^T.
// MODE 1: causal QK^T, triangular-packed lower-tri tiles, XCD-swizzled, bf16 out.
// MODE 2: causal PV, K clipped to (bm+1)*BM, longest-blocks-first.
#define BM 128
#define BN 128
#define BK 32

template<typename OutT, int MODE>
__global__ __launch_bounds__(256) void gemm_bt(
    const u16* __restrict__ A, const u16* __restrict__ B, OutT* __restrict__ C,
    int K, int lda, int ldb, int ldc,
    size_t sA, size_t sB, size_t sC, float alpha) {
  int bn, bm, bz = 0;
  int kEnd = K;
  if (MODE == 0) {
    bm = blockIdx.x >> 3;
    bn = blockIdx.x & 7;
  } else if (MODE == 1) {                // grid 544 = 4 * 136 lower-tri tiles
    int h = blockIdx.x;
    int l = (h & 7) * 68 + (h >> 3);
    bz = l / 136;
    int t = l % 136;
    bm = (int)((sqrtf(8.f * (float)t + 1.f) - 1.f) * 0.5f);
    while ((bm + 1) * (bm + 2) / 2 <= t) ++bm;
    while (bm * (bm + 1) / 2 > t) --bm;
    bn = t - bm * (bm + 1) / 2;
  } else {                               // MODE 2, grid 512
    int l = blockIdx.x;
    bm = 15 - (l >> 5);                  // longest kEnd first
    int rest = l & 31;
    bz = rest >> 3;
    bn = rest & 7;
    kEnd = (K < (bm + 1) * BM) ? K : (bm + 1) * BM;
  }
  const u16* Ag = A + sA * bz + (size_t)bm * BM * lda;
  const u16* Bg = B + sB * bz + (size_t)bn * BN * ldb;
  OutT* Cg = C + sC * bz;

  __shared__ __align__(16) u16 As[2][BM * BK];
  __shared__ __align__(16) u16 Bs[2][BN * BK];

  const int tid = threadIdx.x;
  const int lane = tid & 63, wave = tid >> 6;
  const int wr = wave >> 1, wc = wave & 1;

  const int ch0 = wave, ch1 = wave + 4;
  const int e0 = ch0 * 512 + lane * 8, e1 = ch1 * 512 + lane * 8;
  const int r0 = e0 >> 5, c0 = e0 & 31, r1 = e1 >> 5, c1 = e1 & 31;
  const u16* a0 = Ag + (size_t)r0 * lda + c0;
  const u16* a1 = Ag + (size_t)r1 * lda + c1;
  const u16* b0 = Bg + (size_t)r0 * ldb + c0;
  const u16* b1 = Bg + (size_t)r1 * ldb + c1;

  f32x4 acc[4][4] = {};

  const int fr = lane & 15, kq = (lane >> 4) * 8;
  const int nt = kEnd / BK;

  gload16(a0, &As[0][ch0 * 512]);
  gload16(a1, &As[0][ch1 * 512]);
  gload16(b0, &Bs[0][ch0 * 512]);
  gload16(b1, &Bs[0][ch1 * 512]);
  __syncthreads();

  for (int t = 0; t < nt; ++t) {
    const int cur = t & 1;
    if (t + 1 < nt) {
      const int k0 = (t + 1) * BK;
      gload16(a0 + k0, &As[cur ^ 1][ch0 * 512]);
      gload16(a1 + k0, &As[cur ^ 1][ch1 * 512]);
      gload16(b0 + k0, &Bs[cur ^ 1][ch0 * 512]);
      gload16(b1 + k0, &Bs[cur ^ 1][ch1 * 512]);
    }
    bf16x8 af[4], bfv[4];
    #pragma unroll
    for (int m = 0; m < 4; ++m)
      af[m] = *reinterpret_cast<const bf16x8*>(&As[cur][(wr * 64 + m * 16 + fr) * BK + kq]);
    #pragma unroll
    for (int n = 0; n < 4; ++n)
      bfv[n] = *reinterpret_cast<const bf16x8*>(&Bs[cur][(wc * 64 + n * 16 + fr) * BK + kq]);
    #pragma unroll
    for (int m = 0; m < 4; ++m)
      #pragma unroll
      for (int n = 0; n < 4; ++n)
        acc[m][n] = MF(af[m], bfv[n], acc[m][n]);
    __syncthreads();
  }

  const int row0 = bm * BM + wr * 64 + (lane >> 4) * 4;
  const int col0 = bn * BN + wc * 64 + fr;
  #pragma unroll
  for (int m = 0; m < 4; ++m)
    #pragma unroll
    for (int n = 0; n < 4; ++n) {
      #pragma unroll
      for (int j = 0; j < 4; ++j) {
        float val = acc[m][n][j] * alpha;
        size_t idx = (size_t)(row0 + m * 16 + j) * ldc + (col0 + n * 16);
        if constexpr (sizeof(OutT) == 2) Cg[idx] = f2bf(val);
        else Cg[idx] = val;
      }
    }
}

// ---------------------------------------------------------------- causal softmax (bf16 in/out, in-place)
// scores: [4][2048][2048] bf16. Row r: softmax over t<=s, write bf16 P in place.
__global__ __launch_bounds__(256) void softmax_causal(u16* __restrict__ sc) {
  int r = blockIdx.x;          // 0..8191
  int s = r & 2047;
  u16* row = sc + (size_t)r * 2048;
  int tid = threadIdx.x;
  int t0 = tid * 8;
  u16x8 raw = {0, 0, 0, 0, 0, 0, 0, 0};
  if (t0 <= s) raw = *reinterpret_cast<const u16x8*>(row + t0);
  float v[8];
  float mx = -1e30f;
  #pragma unroll
  for (int j = 0; j < 8; ++j) {
    v[j] = ((t0 + j) <= s) ? bf2f(raw[j]) : -1e30f;
    mx = fmaxf(mx, v[j]);
  }
  #pragma unroll
  for (int o = 32; o; o >>= 1) mx = fmaxf(mx, __shfl_xor(mx, o, 64));
  __shared__ float red[8];
  if ((tid & 63) == 0) red[tid >> 6] = mx;
  __syncthreads();
  mx = fmaxf(fmaxf(red[0], red[1]), fmaxf(red[2], red[3]));
  float p[8];
  float sum = 0.f;
  #pragma unroll
  for (int j = 0; j < 8; ++j) {
    p[j] = ((t0 + j) <= s) ? __expf(v[j] - mx) : 0.f;
    sum += p[j];
  }
  #pragma unroll
  for (int o = 32; o; o >>= 1) sum += __shfl_xor(sum, o, 64);
  if ((tid & 63) == 0) red[4 + (tid >> 6)] = sum;
  __syncthreads();
  sum = red[4] + red[5] + red[6] + red[7];
  float inv = 1.0f / sum;
  u16x8 o8;
  #pragma unroll
  for (int j = 0; j < 8; ++j) o8[j] = f2bf(p[j] * inv);
  if (t0 <= (s | 127))   // PV reads cols < (bm+1)*128 only
    *reinterpret_cast<u16x8*>(row + t0) = o8;
}

// ---------------------------------------------------------------- launcher
extern "C" void kernel_launch(void* const* d_in, const int* in_sizes, int n_in,
                              void* d_out, int out_size, void* d_ws, size_t ws_size,
                              hipStream_t stream) {
  const float* q  = (const float*)d_in[0];
  const float* k  = (const float*)d_in[1];
  const float* v  = (const float*)d_in[2];
  // d_in[3] = attn_mask (causal tril) — handled analytically
  const float* Wq = (const float*)d_in[4];
  const float* Wk = (const float*)d_in[5];
  const float* Wv = (const float*)d_in[6];
  float* out = (float*)d_out;
  char* ws = (char*)d_ws;

  const size_t MB = 1024ull * 1024ull;
  // Layout (peak 80MB). sc (bf16 scores, 32MB) overlays Vp + weight scratch,
  // all dead before QK writes sc.
  u16* sc   = (u16*)ws;               // 0..32MB  bf16 scores [4][2048][2048]
  u16* Vp   = (u16*)(ws + 0 * MB);    // 0..16MB  (dead after transpose)
  u16* wkT  = (u16*)(ws + 16 * MB);   // 2MB (dead after Mt)
  u16* wqT  = (u16*)(ws + 18 * MB);   // 2MB (dead after Mt)
  u16* wsl  = (u16*)(ws + 20 * MB);   // 4MB: slab0 = Mt, slab1 = Wv_bf (dead after proj)
  u16* Xkbf = (u16*)(ws + 32 * MB);   // 16MB (lives through QK)
  u16* Vt   = (u16*)(ws + 48 * MB);   // 16MB (lives through PV)
  u16* Yq   = (u16*)(ws + 64 * MB);   // 16MB (lives through QK)
  (void)in_sizes; (void)n_in; (void)out_size; (void)ws_size;

  // 1. weight transposes (Wk->WkT, Wq->WqT) + Wv cast + Xk cast
  tcast_w<<<dim3(16, 16, 2), 256, 0, stream>>>(Wk, Wq, wkT, wqT);
  cast3_f32_bf16<<<dim3(512, 1, 1), 256, 0, stream>>>(Wv, nullptr, nullptr,
                                                      wsl + 1048576, 0);
  cast3_f32_bf16<<<dim3(4096, 1, 1), 256, 0, stream>>>(k, nullptr, nullptr, Xkbf, 0);

  // 2. Mt = WkT . WqT^T = Wk^T . Wq  (so Yq = Xq.Mt^T = Xq.Wq^T.Wk)
  gemm_bt<u16, 0><<<64, 256, 0, stream>>>(
      wkT, wqT, wsl, 1024, 1024, 1024, 1024, 0, 0, 0, 1.0f);

  // 3. fused projections: Yq = Xq.Mt^T, Vp = Xv.Wv^T (1024 blocks, XCD-swizzled)
  proj_fused<<<1024, 256, 0, stream>>>(q, v, wsl, Yq, Vp);

  // 4. V transpose -> Vt[4][1024][2048]
  transpose_bf16k<<<dim3(16, 32, 4), 256, 0, stream>>>(Vp, Vt);

  // 5. S = Yq . Xk^T (scaled, triangular-packed, XCD-swizzled) -> bf16 scores
  gemm_bt<u16, 1><<<544, 256, 0, stream>>>(
      Yq, Xkbf, sc, 1024, 1024, 1024, 2048,
      (size_t)2048 * 1024, (size_t)2048 * 1024, (size_t)2048 * 2048, 0.03125f);

  // 6. causal softmax, bf16 in/out in place
  softmax_causal<<<8192, 256, 0, stream>>>(sc);

  // 7. PV: P[2048][2048] . Vt[1024][2048]^T -> out f32, longest-first
  gemm_bt<float, 2><<<512, 256, 0, stream>>>(
      sc, Vt, out, 2048, 2048, 2048, 1024,
      (size_t)2048 * 2048, (size_t)1024 * 2048, (size_t)2048 * 1024, 1.0f);
}

// Round 9
// 170.925 us; speedup vs baseline: 1.1273x; 1.1273x over previous
//
#include <hip/hip_runtime.h>
#include <math.h>

using u16 = unsigned short;
typedef __attribute__((ext_vector_type(8))) __bf16 bf16x8;
typedef __attribute__((ext_vector_type(4))) float f32x4;
typedef __attribute__((ext_vector_type(4))) float f4v;
typedef __attribute__((ext_vector_type(8))) u16 u16x8;

__device__ __forceinline__ u16 f2bf(float f) {
  unsigned u = __float_as_uint(f);
  u += 0x7fffu + ((u >> 16) & 1u);   // round-to-nearest-even
  return (u16)(u >> 16);
}
__device__ __forceinline__ float bf2f(u16 b) {
  unsigned u = ((unsigned)b) << 16;
  return __uint_as_float(u);
}

__device__ __forceinline__ void gload16(const void* g, void* l) {
  __builtin_amdgcn_global_load_lds(
      (const __attribute__((address_space(1))) unsigned int*)g,
      (__attribute__((address_space(3))) unsigned int*)l, 16, 0, 0);
}

__device__ __forceinline__ f32x4 MF(bf16x8 a, bf16x8 b, f32x4 c) {
  return __builtin_amdgcn_mfma_f32_16x16x32_bf16(a, b, c, 0, 0, 0);
}

__device__ __forceinline__ bf16x8 pk8(f4v a, f4v b) {
  bf16x8 x;
  x[0] = (__bf16)a[0]; x[1] = (__bf16)a[1]; x[2] = (__bf16)a[2]; x[3] = (__bf16)a[3];
  x[4] = (__bf16)b[0]; x[5] = (__bf16)b[1]; x[6] = (__bf16)b[2]; x[7] = (__bf16)b[3];
  return x;
}

// ---------------------------------------------------------------- cast f32->bf16 (3 tensors)
__global__ __launch_bounds__(256) void cast3_f32_bf16(
    const float* __restrict__ p0, const float* __restrict__ p1,
    const float* __restrict__ p2, u16* __restrict__ out, size_t ostride) {
  int z = blockIdx.z;
  const float* in = (z == 0) ? p0 : (z == 1) ? p1 : p2;
  size_t i = ((size_t)blockIdx.x * 256 + threadIdx.x) * 8;
  f4v a = *reinterpret_cast<const f4v*>(in + i);
  f4v b = *reinterpret_cast<const f4v*>(in + i + 4);
  u16x8 r;
  r[0] = f2bf(a[0]); r[1] = f2bf(a[1]); r[2] = f2bf(a[2]); r[3] = f2bf(a[3]);
  r[4] = f2bf(b[0]); r[5] = f2bf(b[1]); r[6] = f2bf(b[2]); r[7] = f2bf(b[3]);
  *reinterpret_cast<u16x8*>(out + z * ostride + i) = r;
}

// ---------------------------------------------------------------- bf16 transpose
// in: [4][2048][1024]  -> out: [4][1024][2048]
__global__ __launch_bounds__(256) void transpose_bf16k(const u16* __restrict__ in,
                                                       u16* __restrict__ out) {
  __shared__ u16 t[64][65];
  int c0 = blockIdx.x * 64, r0 = blockIdx.y * 64;
  size_t zb = (size_t)blockIdx.z * 2048 * 1024;
  const u16* I = in + zb;
  u16* O = out + zb;
  int tx = threadIdx.x & 63, ty = threadIdx.x >> 6;
  #pragma unroll
  for (int i = 0; i < 64; i += 4)
    t[ty + i][tx] = I[(size_t)(r0 + ty + i) * 1024 + c0 + tx];
  __syncthreads();
  #pragma unroll
  for (int i = 0; i < 64; i += 4)
    O[(size_t)(c0 + ty + i) * 2048 + r0 + tx] = t[tx][ty + i];
}

// ================================================================ fused-cast projection GEMM
// 3 slabs: C[which] = (f32 X[which]) . (bf16 W[which])^T.
// Depth-2 A reg-staging + counted vmcnt(4) raw-barrier protocol (proven R7).
// Grid 1536 flat, XCD-chunked; bm192: 0-63 -> Q, 64-127 -> K, 128-191 -> V.
__global__ __launch_bounds__(256) void proj_fused(
    const float* __restrict__ Aq, const float* __restrict__ Ak,
    const float* __restrict__ Av, const u16* __restrict__ W,
    u16* __restrict__ Qp, u16* __restrict__ Kp, u16* __restrict__ Vp) {
  int h = blockIdx.x;
  int l = (h & 7) * 192 + (h >> 3);    // bijective XCD chunking
  int bn = l & 7;
  int bm192 = l >> 3;
  int which = bm192 >> 6;
  int bm = bm192 & 63;
  const float* Ag = ((which == 0) ? Aq : (which == 1) ? Ak : Av) +
                    (size_t)bm * 128 * 1024;
  const u16* Bg = W + (size_t)which * 1048576 + (size_t)bn * 128 * 1024;
  u16* Cg = (which == 0) ? Qp : (which == 1) ? Kp : Vp;

  __shared__ __align__(16) u16 As[2][128 * 32];   // 2 x 8KB
  __shared__ __align__(16) u16 Bs[2][128 * 32];   // 2 x 8KB

  const int tid = threadIdx.x, lane = tid & 63, wave = tid >> 6;
  const int wr = wave >> 1, wc = wave & 1;
  const int fr = lane & 15, kq = (lane >> 4) * 8;

  const float* ag0 = Ag + (size_t)(tid >> 2) * 1024 + (tid & 3) * 8;
  const float* ag1 = ag0 + 64 * 1024;
  const int w0i = (tid >> 2) * 32 + (tid & 3) * 8;
  const int w1i = w0i + 2048;
  const int ch0 = wave, ch1 = wave + 4;
  const int e0 = ch0 * 512 + lane * 8, e1 = ch1 * 512 + lane * 8;
  const int br0 = e0 >> 5, bc0 = e0 & 31, br1 = e1 >> 5, bc1 = e1 & 31;
  const u16* b0 = Bg + (size_t)br0 * 1024 + bc0;
  const u16* b1 = Bg + (size_t)br1 * 1024 + bc1;

  f32x4 acc[4][4] = {};
  f4v pc0, pc1, pc2, pc3, pn0, pn1, pn2, pn3;

  gload16(b0, &Bs[0][ch0 * 512]);
  gload16(b1, &Bs[0][ch1 * 512]);
  pc0 = *(const f4v*)(ag0);      pc1 = *(const f4v*)(ag0 + 4);
  pc2 = *(const f4v*)(ag1);      pc3 = *(const f4v*)(ag1 + 4);
  pn0 = *(const f4v*)(ag0 + 32); pn1 = *(const f4v*)(ag0 + 36);
  pn2 = *(const f4v*)(ag1 + 32); pn3 = *(const f4v*)(ag1 + 36);
  *(bf16x8*)&As[0][w0i] = pk8(pc0, pc1);
  *(bf16x8*)&As[0][w1i] = pk8(pc2, pc3);
  pc0 = pn0; pc1 = pn1; pc2 = pn2; pc3 = pn3;
  asm volatile("s_waitcnt vmcnt(4)" ::: "memory");
  asm volatile("s_waitcnt lgkmcnt(0)" ::: "memory");
  __builtin_amdgcn_s_barrier();

  for (int t = 0; t < 32; ++t) {
    const int cur = t & 1;
    if (t < 31) {
      const int k0 = (t + 1) * 32;
      gload16(b0 + k0, &Bs[cur ^ 1][ch0 * 512]);
      gload16(b1 + k0, &Bs[cur ^ 1][ch1 * 512]);
    }
    if (t < 30) {
      const float* ap0 = ag0 + (t + 2) * 32;
      const float* ap1 = ag1 + (t + 2) * 32;
      pn0 = *(const f4v*)(ap0); pn1 = *(const f4v*)(ap0 + 4);
      pn2 = *(const f4v*)(ap1); pn3 = *(const f4v*)(ap1 + 4);
    }
    bf16x8 af[4], bfv[4];
    #pragma unroll
    for (int m = 0; m < 4; ++m)
      af[m] = *reinterpret_cast<const bf16x8*>(&As[cur][(wr * 64 + m * 16 + fr) * 32 + kq]);
    #pragma unroll
    for (int n = 0; n < 4; ++n)
      bfv[n] = *reinterpret_cast<const bf16x8*>(&Bs[cur][(wc * 64 + n * 16 + fr) * 32 + kq]);
    #pragma unroll
    for (int m = 0; m < 4; ++m)
      #pragma unroll
      for (int n = 0; n < 4; ++n)
        acc[m][n] = MF(af[m], bfv[n], acc[m][n]);
    if (t < 31) {
      *(bf16x8*)&As[cur ^ 1][w0i] = pk8(pc0, pc1);
      *(bf16x8*)&As[cur ^ 1][w1i] = pk8(pc2, pc3);
      pc0 = pn0; pc1 = pn1; pc2 = pn2; pc3 = pn3;
      if (t < 30) { asm volatile("s_waitcnt vmcnt(4)" ::: "memory"); }
      else        { asm volatile("s_waitcnt vmcnt(0)" ::: "memory"); }
      asm volatile("s_waitcnt lgkmcnt(0)" ::: "memory");
      __builtin_amdgcn_s_barrier();
    }
  }

  const int row0 = bm * 128 + wr * 64 + (lane >> 4) * 4;
  const int col0 = bn * 128 + wc * 64 + fr;
  #pragma unroll
  for (int m = 0; m < 4; ++m)
    #pragma unroll
    for (int n = 0; n < 4; ++n)
      #pragma unroll
      for (int j = 0; j < 4; ++j)
        Cg[(size_t)(row0 + m * 16 + j) * 1024 + (col0 + n * 16)] = f2bf(acc[m][n][j]);
}

// ================================================================ 8-wave 128x128 GEMM
// Same proven 2-phase structure, but 512 threads (8 waves, 2M x 4N; each wave
// 64x32 out, acc[4][2], 8 MFMA/iter). Doubles the wave count of the grid-
// starved QK (544 blocks) and PV (512 blocks) dispatches: 2176->4352 waves.
// Staging: wave w owns A-chunk w and B-chunk w (1KB each), addresses as before.
// MODE 1: causal QK^T, tri-packed, XCD-swizzled, bf16 out (alpha pre-scale).
// MODE 2: causal PV, K clipped to (bm+1)*128, longest-first, f32 out.
template<typename OutT, int MODE>
__global__ __launch_bounds__(512) void gemm_bt8(
    const u16* __restrict__ A, const u16* __restrict__ B, OutT* __restrict__ C,
    int K, int lda, int ldb, int ldc,
    size_t sA, size_t sB, size_t sC, float alpha) {
  int bn, bm, bz;
  int kEnd = K;
  if (MODE == 1) {                       // grid 544 = 4 * 136 lower-tri tiles
    int h = blockIdx.x;
    int l = (h & 7) * 68 + (h >> 3);
    bz = l / 136;
    int t = l % 136;
    bm = (int)((sqrtf(8.f * (float)t + 1.f) - 1.f) * 0.5f);
    while ((bm + 1) * (bm + 2) / 2 <= t) ++bm;
    while (bm * (bm + 1) / 2 > t) --bm;
    bn = t - bm * (bm + 1) / 2;
  } else {                               // MODE 2, grid 512
    int l = blockIdx.x;
    bm = 15 - (l >> 5);                  // longest kEnd first
    int rest = l & 31;
    bz = rest >> 3;
    bn = rest & 7;
    kEnd = (K < (bm + 1) * 128) ? K : (bm + 1) * 128;
  }
  const u16* Ag = A + sA * bz + (size_t)bm * 128 * lda;
  const u16* Bg = B + sB * bz + (size_t)bn * 128 * ldb;
  OutT* Cg = C + sC * bz;

  __shared__ __align__(16) u16 As[2][128 * 32];
  __shared__ __align__(16) u16 Bs[2][128 * 32];

  const int tid = threadIdx.x;
  const int lane = tid & 63, wv = tid >> 6;   // 8 waves
  const int wr = wv >> 2, wc = wv & 3;        // 2M x 4N
  const int fr = lane & 15, kq = (lane >> 4) * 8;

  // staging: wave wv owns A-chunk wv + B-chunk wv (1KB each)
  const int e0 = wv * 512 + lane * 8;
  const int r0 = e0 >> 5, c0 = e0 & 31;
  const u16* a0 = Ag + (size_t)r0 * lda + c0;
  const u16* b0 = Bg + (size_t)r0 * ldb + c0;

  f32x4 acc[4][2] = {};
  const int nt = kEnd / 32;

  gload16(a0, &As[0][wv * 512]);
  gload16(b0, &Bs[0][wv * 512]);
  __syncthreads();

  for (int t = 0; t < nt; ++t) {
    const int cur = t & 1;
    if (t + 1 < nt) {
      const int k0 = (t + 1) * 32;
      gload16(a0 + k0, &As[cur ^ 1][wv * 512]);
      gload16(b0 + k0, &Bs[cur ^ 1][wv * 512]);
    }
    bf16x8 af[4], bfv[2];
    #pragma unroll
    for (int m = 0; m < 4; ++m)
      af[m] = *reinterpret_cast<const bf16x8*>(&As[cur][(wr * 64 + m * 16 + fr) * 32 + kq]);
    #pragma unroll
    for (int n = 0; n < 2; ++n)
      bfv[n] = *reinterpret_cast<const bf16x8*>(&Bs[cur][(wc * 32 + n * 16 + fr) * 32 + kq]);
    #pragma unroll
    for (int m = 0; m < 4; ++m)
      #pragma unroll
      for (int n = 0; n < 2; ++n)
        acc[m][n] = MF(af[m], bfv[n], acc[m][n]);
    __syncthreads();
  }

  const int row0 = bm * 128 + wr * 64 + (lane >> 4) * 4;
  const int col0 = bn * 128 + wc * 32 + fr;
  #pragma unroll
  for (int m = 0; m < 4; ++m)
    #pragma unroll
    for (int n = 0; n < 2; ++n) {
      #pragma unroll
      for (int j = 0; j < 4; ++j) {
        float val = acc[m][n][j] * alpha;
        size_t idx = (size_t)(row0 + m * 16 + j) * ldc + (col0 + n * 16);
        if constexpr (sizeof(OutT) == 2) Cg[idx] = f2bf(val);
        else Cg[idx] = val;
      }
    }
}

// ---------------------------------------------------------------- causal softmax (bf16 in/out, in-place)
// scores: [4][2048][2048] bf16. Row r: softmax over t<=s, write bf16 P in place.
__global__ __launch_bounds__(256) void softmax_causal(u16* __restrict__ sc) {
  int r = blockIdx.x;          // 0..8191
  int s = r & 2047;
  u16* row = sc + (size_t)r * 2048;
  int tid = threadIdx.x;
  int t0 = tid * 8;
  u16x8 raw = {0, 0, 0, 0, 0, 0, 0, 0};
  if (t0 <= s) raw = *reinterpret_cast<const u16x8*>(row + t0);
  float v[8];
  float mx = -1e30f;
  #pragma unroll
  for (int j = 0; j < 8; ++j) {
    v[j] = ((t0 + j) <= s) ? bf2f(raw[j]) : -1e30f;
    mx = fmaxf(mx, v[j]);
  }
  #pragma unroll
  for (int o = 32; o; o >>= 1) mx = fmaxf(mx, __shfl_xor(mx, o, 64));
  __shared__ float red[8];
  if ((tid & 63) == 0) red[tid >> 6] = mx;
  __syncthreads();
  mx = fmaxf(fmaxf(red[0], red[1]), fmaxf(red[2], red[3]));
  float p[8];
  float sum = 0.f;
  #pragma unroll
  for (int j = 0; j < 8; ++j) {
    p[j] = ((t0 + j) <= s) ? __expf(v[j] - mx) : 0.f;
    sum += p[j];
  }
  #pragma unroll
  for (int o = 32; o; o >>= 1) sum += __shfl_xor(sum, o, 64);
  if ((tid & 63) == 0) red[4 + (tid >> 6)] = sum;
  __syncthreads();
  sum = red[4] + red[5] + red[6] + red[7];
  float inv = 1.0f / sum;
  u16x8 o8;
  #pragma unroll
  for (int j = 0; j < 8; ++j) o8[j] = f2bf(p[j] * inv);
  if (t0 <= (s | 127))   // PV reads cols < (bm+1)*128 only
    *reinterpret_cast<u16x8*>(row + t0) = o8;
}

// ---------------------------------------------------------------- launcher
extern "C" void kernel_launch(void* const* d_in, const int* in_sizes, int n_in,
                              void* d_out, int out_size, void* d_ws, size_t ws_size,
                              hipStream_t stream) {
  const float* q  = (const float*)d_in[0];
  const float* k  = (const float*)d_in[1];
  const float* v  = (const float*)d_in[2];
  // d_in[3] = attn_mask (causal tril) — handled analytically
  const float* Wq = (const float*)d_in[4];
  const float* Wk = (const float*)d_in[5];
  const float* Wv = (const float*)d_in[6];
  float* out = (float*)d_out;
  char* ws = (char*)d_ws;

  const size_t MB = 1024ull * 1024ull;
  // Liveness: Vp (dead after transpose) & wqb (dead after proj) precede sc (QK).
  u16* sc   = (u16*)ws;               // 0..32MB  bf16 scores [4][2048][2048]
  u16* Vp   = (u16*)(ws + 0 * MB);    // 16MB (dead after transpose)
  u16* wqb  = (u16*)(ws + 16 * MB);   // 6MB  (dead after proj)
  u16* Vt   = (u16*)(ws + 64 * MB);   // 16MB
  u16* Kp   = (u16*)(ws + 80 * MB);   // 16MB
  u16* Qp   = (u16*)(ws + 96 * MB);   // 16MB  -> peak 112MB
  (void)in_sizes; (void)n_in; (void)out_size; (void)ws_size;

  // 1. cast weights only (Q/K/V input cast is fused into the projection)
  cast3_f32_bf16<<<dim3(512, 1, 3), 256, 0, stream>>>(Wq, Wk, Wv, wqb, 1048576);

  // 2. fused-cast projections (1536 blocks, XCD-swizzled, depth-2 reg staging)
  proj_fused<<<1536, 256, 0, stream>>>(q, k, v, wqb, Qp, Kp, Vp);

  // 3. V transpose -> Vt[4][1024][2048]
  transpose_bf16k<<<dim3(16, 32, 4), 256, 0, stream>>>(Vp, Vt);

  // 4. QK^T (scaled, tri-packed, XCD-swizzled, 8-wave) -> bf16 scores
  gemm_bt8<u16, 1><<<544, 512, 0, stream>>>(
      Qp, Kp, sc, 1024, 1024, 1024, 2048,
      (size_t)2048 * 1024, (size_t)2048 * 1024, (size_t)2048 * 2048, 0.03125f);

  // 5. causal softmax, bf16 in/out in place
  softmax_causal<<<8192, 256, 0, stream>>>(sc);

  // 6. PV: P[2048][2048] . Vt[1024][2048]^T -> out f32, longest-first, 8-wave
  gemm_bt8<float, 2><<<512, 512, 0, stream>>>(
      sc, Vt, out, 2048, 2048, 2048, 1024,
      (size_t)2048 * 2048, (size_t)1024 * 2048, (size_t)2048 * 1024, 1.0f);
}